// Round 16
// baseline (297.696 us; speedup 1.0000x reference)
//
#include <hip/hip_runtime.h>
#include <cstdint>

typedef _Float16 h2 __attribute__((ext_vector_type(2)));
typedef _Float16 h4 __attribute__((ext_vector_type(4)));
typedef _Float16 h8 __attribute__((ext_vector_type(8)));
typedef float f32x4 __attribute__((ext_vector_type(4)));
typedef float f32x16 __attribute__((ext_vector_type(16)));

__device__ __forceinline__ h2 cvt_pk(float a, float b) {
  return __builtin_bit_cast(h2, __builtin_amdgcn_cvt_pkrtz(a, b));
}

// single-instruction 2^x (exp2f without fast-math lowers to a multi-op ocml sequence)
__device__ __forceinline__ float exp2_raw(float x) {
  float r;
  asm("v_exp_f32 %0, %1" : "=v"(r) : "v"(x));
  return r;
}

// ---------- async global->LDS, 16B per lane, wave-uniform LDS base ----------
__device__ __forceinline__ void g2l16(const void* g, void* l) {
  __builtin_amdgcn_global_load_lds(
      (__attribute__((address_space(1))) void*)(uintptr_t)(g),
      (__attribute__((address_space(3))) void*)(l), 16, 0, 0);
}

// ---------------- fp32 -> fp16 elementwise ----------------
__global__ __launch_bounds__(256) void convk(const float* __restrict__ in,
                                             _Float16* __restrict__ out, int n) {
  int i = (blockIdx.x * 256 + threadIdx.x) * 4;
  if (i + 3 < n) {
    const float4 v = *(const float4*)(in + i);
    h4 o;
    o[0] = (_Float16)v.x; o[1] = (_Float16)v.y; o[2] = (_Float16)v.z; o[3] = (_Float16)v.w;
    *(h4*)(out + i) = o;
  }
}

// ---------------- fp32 [R][C] -> fp16 [C][R] transpose-convert ----------------
__global__ __launch_bounds__(256) void transconv_k(const float* __restrict__ in,
                                                   _Float16* __restrict__ out,
                                                   int R, int C) {
  __shared__ float tile[64][65];
  const int tC = C >> 6;
  const int bc = blockIdx.x % tC, br = blockIdx.x / tC;
  const int r0 = br << 6, c0 = bc << 6;
  const int t = threadIdx.x;
  const int lr = t >> 4, lc = (t & 15) << 2;
#pragma unroll
  for (int p = 0; p < 4; ++p) {
    const float4 v = *(const float4*)(in + (size_t)(r0 + p * 16 + lr) * C + c0 + lc);
    tile[p * 16 + lr][lc + 0] = v.x;
    tile[p * 16 + lr][lc + 1] = v.y;
    tile[p * 16 + lr][lc + 2] = v.z;
    tile[p * 16 + lr][lc + 3] = v.w;
  }
  __syncthreads();
#pragma unroll
  for (int p = 0; p < 4; ++p) {
    const int oc = p * 16 + lr;  // out-row = in-col
    h4 v;
#pragma unroll
    for (int e = 0; e < 4; ++e) v[e] = (_Float16)tile[lc + e][oc];
    *(h4*)(out + (size_t)(c0 + oc) * R + r0 + lc) = v;
  }
}

// ---- staging for the BK=32 kernel (gemm2): rows of 32 fp16 (64B), XOR (row&6)<<3 ----
__device__ __forceinline__ void stage_chunk(const _Float16* X, int R0, int K, int kof,
                                            _Float16* ldsbase, int chunk, int lane) {
  const int b = chunk * 1024 + lane * 16;           // linear LDS byte offset
  const int l = b ^ (((b >> 6) & 6) << 3);          // logical byte (involution)
  const _Float16* src = X + (size_t)(R0 + (l >> 6)) * K + kof + ((l & 63) >> 1);
  g2l16(src, (char*)ldsbase + chunk * 1024);
}

// ---------------- GEMM (gemm2): BM=256 BN=128 BK=32, 512 thr, 2-phase dbuf ----------------
// R12-measured best for MODE0. (124us-class structure: MfmaUtil 38.7%, VGPR 60.)
__global__ __launch_bounds__(512) void gemm_k(
    const _Float16* __restrict__ A, const _Float16* __restrict__ BT,
    const int K, const int NTILES, float* __restrict__ fo) {
  __shared__ __align__(16) _Float16 Ls[2][12288];  // [dbuf][A:8192 | B:4096] = 48KB
  const int tid = threadIdx.x;
  const int cpx = gridDim.x >> 3;
  const int xcd = blockIdx.x & 7, idx = blockIdx.x >> 3;
  const int MBC = cpx / NTILES;
  const int grp = idx >> 3, sub = idx & 7;
  const int bt = grp * 4 + (sub & 3);
  const int mb = xcd * MBC + (sub >> 2);
  const int m0 = mb * 256, n0 = bt * 128;
  const int wid = tid >> 6, lane = tid & 63;
  const int wr = wid >> 1, wc = wid & 1;  // 4 x 2 waves
  const int g = lane >> 4, c = lane & 15;

  f32x4 acc[4][4];
#pragma unroll
  for (int i = 0; i < 4; ++i)
#pragma unroll
    for (int j = 0; j < 4; ++j)
#pragma unroll
      for (int e = 0; e < 4; ++e) acc[i][j][e] = 0.f;

  const int sx = (c & 6) << 3;
  const int nk = K >> 5;

#pragma unroll
  for (int t0 = 0; t0 < 2; ++t0) {
    stage_chunk(A, m0, K, t0 * 32, Ls[t0], (0 * 8 + wid), lane);
    stage_chunk(A, m0, K, t0 * 32, Ls[t0], (1 * 8 + wid), lane);
    stage_chunk(BT, n0, K, t0 * 32, Ls[t0] + 8192, wid, lane);
  }

  for (int kt = 0; kt < nk; ++kt) {
    if (kt < nk - 1) {
      asm volatile("s_waitcnt vmcnt(3)" ::: "memory");
    } else {
      asm volatile("s_waitcnt vmcnt(0)" ::: "memory");
    }
    __builtin_amdgcn_s_barrier();
    const int db = kt & 1;
    const _Float16* Ab = Ls[db];
    const _Float16* Bb = Ls[db] + 8192;
    h8 af[4], bf[4];
#pragma unroll
    for (int t = 0; t < 4; ++t) {
      const int lg = (wr * 64 + t * 16 + c) * 64 + 16 * g;
      af[t] = *(const h8*)((const char*)Ab + (lg ^ sx));
    }
#pragma unroll
    for (int t = 0; t < 4; ++t) {
      const int lg = (wc * 64 + t * 16 + c) * 64 + 16 * g;
      bf[t] = *(const h8*)((const char*)Bb + (lg ^ sx));
    }
    __builtin_amdgcn_s_setprio(1);
#pragma unroll
    for (int i = 0; i < 4; ++i)
#pragma unroll
      for (int j = 0; j < 4; ++j)
        acc[i][j] = __builtin_amdgcn_mfma_f32_16x16x32_f16(af[i], bf[j], acc[i][j], 0, 0, 0);
    __builtin_amdgcn_s_setprio(0);
    __builtin_amdgcn_s_barrier();
    const int nx = kt + 2;
    if (nx < nk) {
      stage_chunk(A, m0, K, nx * 32, Ls[db], (0 * 8 + wid), lane);
      stage_chunk(A, m0, K, nx * 32, Ls[db], (1 * 8 + wid), lane);
      stage_chunk(BT, n0, K, nx * 32, Ls[db] + 8192, wid, lane);
    }
  }

  const int Ncols = NTILES * 128;
#pragma unroll
  for (int mt = 0; mt < 4; ++mt)
#pragma unroll
    for (int i = 0; i < 4; ++i) {
      const int m = m0 + wr * 64 + mt * 16 + 4 * g + i;
      float* orow = fo + (size_t)m * Ncols + n0 + wc * 64 + c;
#pragma unroll
      for (int nt = 0; nt < 4; ++nt) orow[nt * 16] = acc[mt][nt][i];
    }
}

// ---------------- GEMM1 (QKV): m201-style phase-interleaved schedule ----------------
// BM=256 BN=128 BK=64, 512 thr (8 waves 4x2, 64x64/wave, acc[4][4] -- epilogue identical
// to the proven kernel). LDS 96KB = 2 dbuf x [A 256x64 (32KB) | B 128x64 (16KB)], 1 blk/CU.
// Per K-tile: 2 phases (kk=0/1): {8 ds_read_b128 || stage half of tile t+1 -> buf^1;
// barrier; lgkmcnt(0)+sched_barrier (rule #18); setprio(1) 16 MFMA setprio(0); barrier},
// then tail {vmcnt(0); barrier} publishes tile t+1 (once per K-tile, not per phase).
// Ledger: stage into buf^1 at iter t is safe because every wave's reads of buf^1
// (iter t-1) completed before its own lgkmcnt(0), which precedes the tail barrier all
// waves passed. Tile-t readiness: each wave drains its OWN 6 stage loads (vmcnt 0)
// BEFORE the tail barrier -> after the barrier the whole tile is resident.
// Swizzle for 128B rows: phys = log ^ (((log>>7)&7)<<4); read slot (4kk+g)^(c&7)
// spreads 64 lanes evenly over all 8 bank-groups (8 lanes each) = conflict-free.
// Staging pre-swizzles the per-lane GLOBAL source; LDS dest stays linear (both-sides rule).
__global__ __launch_bounds__(512) void gemm8_k(
    const _Float16* __restrict__ A, const _Float16* __restrict__ BT,
    const int K, const int NTILES,
    _Float16* __restrict__ outq, _Float16* __restrict__ outk,
    _Float16* __restrict__ outv, const float* __restrict__ freqs) {
  __shared__ __align__(16) _Float16 Ls[2][24576];  // 96KB
  const int tid = threadIdx.x;
  const int cpx = gridDim.x >> 3;
  const int xcd = blockIdx.x & 7, idx = blockIdx.x >> 3;
  const int MBC = cpx / NTILES;
  const int grp = idx >> 3, sub = idx & 7;
  const int bt = grp * 4 + (sub & 3);
  const int mb = xcd * MBC + (sub >> 2);
  const int m0 = mb * 256, n0 = bt * 128;
  const int wid = tid >> 6, lane = tid & 63;
  const int wr = wid >> 1, wc = wid & 1;  // 4 x 2 waves
  const int g = lane >> 4, c = lane & 15;

  f32x4 acc[4][4];
#pragma unroll
  for (int i = 0; i < 4; ++i)
#pragma unroll
    for (int j = 0; j < 4; ++j)
#pragma unroll
      for (int e = 0; e < 4; ++e) acc[i][j][e] = 0.f;

  // staging sources (per-lane, pre-swizzled) + wave-uniform LDS dests
  const _Float16* srcA[4];
  int dstA[4];
#pragma unroll
  for (int a = 0; a < 4; ++a) {
    const int h = a >> 1, q = a & 1;
    const int d = h * 16384 + q * 8192 + wid * 1024;  // dest byte in A region
    const int b = d + lane * 16;
    const int l = b ^ (((b >> 7) & 7) << 4);
    srcA[a] = A + (size_t)(m0 + (l >> 7)) * K + ((l & 127) >> 1);
    dstA[a] = d;
  }
  const _Float16* srcB[2];
  int dstB[2];
#pragma unroll
  for (int q = 0; q < 2; ++q) {
    const int d = q * 8192 + wid * 1024;              // region-local
    const int b = d + lane * 16;
    const int l = b ^ (((b >> 7) & 7) << 4);
    srcB[q] = BT + (size_t)(n0 + (l >> 7)) * K + ((l & 127) >> 1);
    dstB[q] = 32768 + d;                               // B region starts at byte 32768
  }

  // fragment read byte-offsets (loop-invariant)
  int aoff[2][4], boff[2][4];
#pragma unroll
  for (int kk = 0; kk < 2; ++kk)
#pragma unroll
    for (int t = 0; t < 4; ++t) {
      const int ra = (wr * 64 + t * 16 + c);
      const int rb = (wc * 64 + t * 16 + c);
      aoff[kk][t] = (ra * 128 + kk * 64 + 16 * g) ^ ((c & 7) << 4);
      boff[kk][t] = 32768 + ((rb * 128 + kk * 64 + 16 * g) ^ ((c & 7) << 4));
    }

  const int nk = K >> 6;  // K-tiles of 64

  // prologue: stage tile 0 into buf 0; drain; publish
#pragma unroll
  for (int a = 0; a < 4; ++a) g2l16(srcA[a], (char*)Ls[0] + dstA[a]);
#pragma unroll
  for (int q = 0; q < 2; ++q) g2l16(srcB[q], (char*)Ls[0] + dstB[q]);
  asm volatile("s_waitcnt vmcnt(0)" ::: "memory");
  __builtin_amdgcn_s_barrier();

  for (int kt = 0; kt < nk; ++kt) {
    const int db = kt & 1;
    const char* Lb = (const char*)Ls[db];
    char* Ln = (char*)Ls[db ^ 1];
    const int kof = (kt + 1) << 6;
    const bool pf = (kt + 1 < nk);
    h8 af[4], bf[4];

    // ---- phase 0 (kk = 0) ----
#pragma unroll
    for (int t = 0; t < 4; ++t) af[t] = *(const h8*)(Lb + aoff[0][t]);
#pragma unroll
    for (int t = 0; t < 4; ++t) bf[t] = *(const h8*)(Lb + boff[0][t]);
    if (pf) {
#pragma unroll
      for (int a = 0; a < 4; ++a) g2l16(srcA[a] + kof, Ln + dstA[a]);
    }
    __builtin_amdgcn_s_barrier();
    asm volatile("s_waitcnt lgkmcnt(0)" ::: "memory");
    __builtin_amdgcn_sched_barrier(0);
    __builtin_amdgcn_s_setprio(1);
#pragma unroll
    for (int i = 0; i < 4; ++i)
#pragma unroll
      for (int j = 0; j < 4; ++j)
        acc[i][j] = __builtin_amdgcn_mfma_f32_16x16x32_f16(af[i], bf[j], acc[i][j], 0, 0, 0);
    __builtin_amdgcn_s_setprio(0);
    __builtin_amdgcn_s_barrier();

    // ---- phase 1 (kk = 1) ----
#pragma unroll
    for (int t = 0; t < 4; ++t) af[t] = *(const h8*)(Lb + aoff[1][t]);
#pragma unroll
    for (int t = 0; t < 4; ++t) bf[t] = *(const h8*)(Lb + boff[1][t]);
    if (pf) {
#pragma unroll
      for (int q = 0; q < 2; ++q) g2l16(srcB[q] + kof, Ln + dstB[q]);
    }
    __builtin_amdgcn_s_barrier();
    asm volatile("s_waitcnt lgkmcnt(0)" ::: "memory");
    __builtin_amdgcn_sched_barrier(0);
    __builtin_amdgcn_s_setprio(1);
#pragma unroll
    for (int i = 0; i < 4; ++i)
#pragma unroll
      for (int j = 0; j < 4; ++j)
        acc[i][j] = __builtin_amdgcn_mfma_f32_16x16x32_f16(af[i], bf[j], acc[i][j], 0, 0, 0);
    __builtin_amdgcn_s_setprio(0);
    __builtin_amdgcn_s_barrier();

    // ---- tail: publish tile t+1 (per-wave drain BEFORE shared barrier) ----
    if (pf) {
      asm volatile("s_waitcnt vmcnt(0)" ::: "memory");
      __builtin_amdgcn_s_barrier();
    }
  }

  // ---- MODE1 epilogue (identical to proven kernel) ----
  const int hh = ((bt & 15) << 1) | wc;  // head 0..31 within its third
  const int third = bt >> 4;             // 0=q 1=k 2=v
  if (third < 2) {
    _Float16* dst0 = (third == 0) ? outq : outk;
#pragma unroll
    for (int mt = 0; mt < 4; ++mt) {
      float ss[4];
#pragma unroll
      for (int i = 0; i < 4; ++i) {
        float s = 0.f;
#pragma unroll
        for (int nt = 0; nt < 4; ++nt) { const float v = acc[mt][nt][i]; s += v * v; }
        ss[i] = s;
      }
#pragma unroll
      for (int msk = 1; msk < 16; msk <<= 1)
#pragma unroll
        for (int i = 0; i < 4; ++i) ss[i] += __shfl_xor(ss[i], msk);
#pragma unroll
      for (int i = 0; i < 4; ++i) {
        const int m = m0 + wr * 64 + mt * 16 + 4 * g + i;
        const int b = m >> 11, pos = m & 2047;
        float inv = 1.0f / fmaxf(sqrtf(ss[i]), 1e-12f);
        if (third == 0) inv *= 0.1803368801f;  // 0.125 * log2(e) folded into q
        const float v0 = acc[mt][0][i] * inv, v1 = acc[mt][1][i] * inv;
        const float v2 = acc[mt][2][i] * inv, v3 = acc[mt][3][i] * inv;
        float sn, cs;
        __sincosf(freqs[pos * 32 + c], &sn, &cs);
        _Float16* d = dst0 + ((size_t)((b << 5) | hh) * 64 + (pos >> 5)) * 2048 +
                      ((c >> 3) * 32 + (pos & 31)) * 8 + (c & 7);
        d[0]    = (_Float16)(v0 * cs - v1 * sn);
        d[512]  = (_Float16)(v1 * cs + v0 * sn);
        d[1024] = (_Float16)v2;
        d[1536] = (_Float16)v3;
      }
    }
  } else {
#pragma unroll
    for (int mt = 0; mt < 4; ++mt)
#pragma unroll
      for (int i = 0; i < 4; ++i) {
        const int m = m0 + wr * 64 + mt * 16 + 4 * g + i;
        const int b = m >> 11, pos = m & 2047;
        const int kvb = pos >> 5, sub2 = (pos >> 4) & 1, rem = pos & 15;
        const int vhi = (rem >> 2) & 1;
        const int vj = (rem & 3) + ((rem >> 3) << 2);
        const size_t hbase = ((size_t)((b << 5) | hh) * 64 + kvb) * 2048;
#pragma unroll
        for (int nt = 0; nt < 4; ++nt) {
          const int dta = nt >> 1;
          const int lfrag = vhi * 32 + (nt & 1) * 16 + c;
          outv[hbase + ((dta * 2 + sub2) * 64 + lfrag) * 8 + vj] = (_Float16)acc[mt][nt][i];
        }
      }
  }
}

// ---------------- flash attention (R15-frozen): swapped QK^T, reg-dbuf K/V ----------------
__global__ __launch_bounds__(256) void attn_k(const _Float16* __restrict__ qf_,
                                              const _Float16* __restrict__ kf_,
                                              const _Float16* __restrict__ vf_,
                                              _Float16* __restrict__ attno) {
  const int tid = threadIdx.x;
  const int wid = tid >> 6;
  const int lane = tid & 63;
  const int l31 = tid & 31;
  const int hi = (tid >> 5) & 1;
  const int dd = blockIdx.x;
  const int xcd = dd & 7, j = dd >> 3;
  const int bh = xcd * 8 + (j >> 4);
  const int qg = j & 15;
  const int qb = (qg << 2) | wid;
  const int q = qb * 32 + l31;

  const _Float16* qp = qf_ + ((size_t)bh * 64 + qb) * 2048 + lane * 8;
  h8 qfr[4];
#pragma unroll
  for (int dc = 0; dc < 4; ++dc) qfr[dc] = *(const h8*)(qp + dc * 512);

  const _Float16* kp = kf_ + (size_t)bh * 64 * 2048 + lane * 8;
  const _Float16* vp = vf_ + (size_t)bh * 64 * 2048 + lane * 8;

  f32x16 acc0, acc1;
#pragma unroll
  for (int e = 0; e < 16; ++e) { acc0[e] = 0.f; acc1[e] = 0.f; }
  float l0 = 0.f, l1 = 0.f, l2 = 0.f, l3 = 0.f;

  auto compute = [&](h8 k0, h8 k1, h8 k2, h8 k3, h8 w00, h8 w01, h8 w10, h8 w11) {
    f32x16 S;
#pragma unroll
    for (int e = 0; e < 16; ++e) S[e] = 0.f;
    __builtin_amdgcn_s_setprio(1);
    S = __builtin_amdgcn_mfma_f32_32x32x16_f16(k0, qfr[0], S, 0, 0, 0);
    S = __builtin_amdgcn_mfma_f32_32x32x16_f16(k1, qfr[1], S, 0, 0, 0);
    S = __builtin_amdgcn_mfma_f32_32x32x16_f16(k2, qfr[2], S, 0, 0, 0);
    S = __builtin_amdgcn_mfma_f32_32x32x16_f16(k3, qfr[3], S, 0, 0, 0);
    __builtin_amdgcn_s_setprio(0);
    float p[16];
#pragma unroll
    for (int e = 0; e < 16; ++e) p[e] = exp2_raw(S[e]);
    l0 += p[0]; l1 += p[1]; l2 += p[2]; l3 += p[3];
    l0 += p[4]; l1 += p[5]; l2 += p[6]; l3 += p[7];
    l0 += p[8]; l1 += p[9]; l2 += p[10]; l3 += p[11];
    l0 += p[12]; l1 += p[13]; l2 += p[14]; l3 += p[15];
    h2 c0 = cvt_pk(p[0], p[1]);
    h2 c1 = cvt_pk(p[2], p[3]);
    h2 c2 = cvt_pk(p[4], p[5]);
    h2 c3 = cvt_pk(p[6], p[7]);
    h2 c4 = cvt_pk(p[8], p[9]);
    h2 c5 = cvt_pk(p[10], p[11]);
    h2 c6 = cvt_pk(p[12], p[13]);
    h2 c7 = cvt_pk(p[14], p[15]);
    h4 x0 = __builtin_shufflevector(c0, c1, 0, 1, 2, 3);
    h4 x1 = __builtin_shufflevector(c2, c3, 0, 1, 2, 3);
    h4 x2 = __builtin_shufflevector(c4, c5, 0, 1, 2, 3);
    h4 x3 = __builtin_shufflevector(c6, c7, 0, 1, 2, 3);
    h8 pb0 = __builtin_shufflevector(x0, x1, 0, 1, 2, 3, 4, 5, 6, 7);
    h8 pb1 = __builtin_shufflevector(x2, x3, 0, 1, 2, 3, 4, 5, 6, 7);
    __builtin_amdgcn_s_setprio(1);
    acc0 = __builtin_amdgcn_mfma_f32_32x32x16_f16(w00, pb0, acc0, 0, 0, 0);
    acc0 = __builtin_amdgcn_mfma_f32_32x32x16_f16(w01, pb1, acc0, 0, 0, 0);
    acc1 = __builtin_amdgcn_mfma_f32_32x32x16_f16(w10, pb0, acc1, 0, 0, 0);
    acc1 = __builtin_amdgcn_mfma_f32_32x32x16_f16(w11, pb1, acc1, 0, 0, 0);
    __builtin_amdgcn_s_setprio(0);
  };

  h8 kA0 = *(const h8*)(kp);
  h8 kA1 = *(const h8*)(kp + 512);
  h8 kA2 = *(const h8*)(kp + 1024);
  h8 kA3 = *(const h8*)(kp + 1536);
  h8 vA0 = *(const h8*)(vp);
  h8 vA1 = *(const h8*)(vp + 512);
  h8 vA2 = *(const h8*)(vp + 1024);
  h8 vA3 = *(const h8*)(vp + 1536);

  for (int it = 0; it < 64; it += 2) {
    const _Float16* kb1 = kp + (size_t)(it + 1) * 2048;
    const _Float16* vb1 = vp + (size_t)(it + 1) * 2048;
    h8 kB0 = *(const h8*)(kb1);
    h8 kB1 = *(const h8*)(kb1 + 512);
    h8 kB2 = *(const h8*)(kb1 + 1024);
    h8 kB3 = *(const h8*)(kb1 + 1536);
    h8 vB0 = *(const h8*)(vb1);
    h8 vB1 = *(const h8*)(vb1 + 512);
    h8 vB2 = *(const h8*)(vb1 + 1024);
    h8 vB3 = *(const h8*)(vb1 + 1536);

    compute(kA0, kA1, kA2, kA3, vA0, vA1, vA2, vA3);

    if (it + 2 < 64) {
      const _Float16* kb2 = kp + (size_t)(it + 2) * 2048;
      const _Float16* vb2 = vp + (size_t)(it + 2) * 2048;
      kA0 = *(const h8*)(kb2);
      kA1 = *(const h8*)(kb2 + 512);
      kA2 = *(const h8*)(kb2 + 1024);
      kA3 = *(const h8*)(kb2 + 1536);
      vA0 = *(const h8*)(vb2);
      vA1 = *(const h8*)(vb2 + 512);
      vA2 = *(const h8*)(vb2 + 1024);
      vA3 = *(const h8*)(vb2 + 1536);
    }

    compute(kB0, kB1, kB2, kB3, vB0, vB1, vB2, vB3);
  }

  float lsum = (l0 + l1) + (l2 + l3);
  lsum += __shfl_xor(lsum, 32);
  const float inv = 1.0f / lsum;

  const int b = bh >> 5, h = bh & 31;
  _Float16* orow = attno + ((size_t)b * 2048 + q) * 2048 + h * 64;
#pragma unroll
  for (int dta = 0; dta < 2; ++dta) {
#pragma unroll
    for (int blk = 0; blk < 4; ++blk) {
      h4 st;
#pragma unroll
      for (int e = 0; e < 4; ++e) {
        const float v = (dta == 0) ? acc0[blk * 4 + e] : acc1[blk * 4 + e];
        st[e] = (_Float16)(v * inv);
      }
      *(h4*)(orow + dta * 32 + blk * 8 + 4 * hi) = st;
    }
  }
}

extern "C" void kernel_launch(void* const* d_in, const int* in_sizes, int n_in,
                              void* d_out, int out_size, void* d_ws, size_t ws_size,
                              hipStream_t stream) {
  const float* x = (const float*)d_in[0];
  const float* wqkv = (const float*)d_in[1];
  const float* wout = (const float*)d_in[2];
  const float* freqs = (const float*)d_in[3];
  char* ws = (char*)d_ws;
  _Float16* xb    = (_Float16*)ws;                          // [0,16M)  gemm1 A input
  _Float16* attno = xb;                                     // [0,16M)  attn out (x dead)
  _Float16* wqkvT = (_Float16*)(ws + (size_t)(16 << 20));   // [16,40M) gemm1 B input
  _Float16* woutT = (_Float16*)(ws + (size_t)(40 << 20));   // [40,48M)
  _Float16* qn    = (_Float16*)(ws + (size_t)(48 << 20));   // [48,64M) q-frags
  _Float16* kn    = (_Float16*)(ws + (size_t)(64 << 20));   // [64,80M) k-frags
  _Float16* vT    = (_Float16*)(ws + (size_t)(80 << 20));   // [80,96M) v-frags
  float* out = (float*)d_out;

  convk<<<8192, 256, 0, stream>>>(x, xb, 2 * 2048 * 2048);
  transconv_k<<<(6144 / 64) * (2048 / 64), 256, 0, stream>>>(wqkv, wqkvT, 2048, 6144);
  transconv_k<<<(2048 / 64) * (2048 / 64), 256, 0, stream>>>(wout, woutT, 2048, 2048);
  gemm8_k<<<16 * 48, 512, 0, stream>>>(xb, wqkvT, 2048, 48, qn, kn, vT, freqs);
  attn_k<<<1024, 256, 0, stream>>>(qn, kn, vT, attno);
  gemm_k<<<16 * 16, 512, 0, stream>>>(attno, woutT, 2048, 16, out);
}

// Round 17
// 293.175 us; speedup vs baseline: 1.0154x; 1.0154x over previous
//
#include <hip/hip_runtime.h>
#include <cstdint>

typedef _Float16 h2 __attribute__((ext_vector_type(2)));
typedef _Float16 h4 __attribute__((ext_vector_type(4)));
typedef _Float16 h8 __attribute__((ext_vector_type(8)));
typedef float f32x4 __attribute__((ext_vector_type(4)));
typedef float f32x16 __attribute__((ext_vector_type(16)));

__device__ __forceinline__ h2 cvt_pk(float a, float b) {
  return __builtin_bit_cast(h2, __builtin_amdgcn_cvt_pkrtz(a, b));
}

// single-instruction 2^x (exp2f without fast-math lowers to a multi-op ocml sequence)
__device__ __forceinline__ float exp2_raw(float x) {
  float r;
  asm("v_exp_f32 %0, %1" : "=v"(r) : "v"(x));
  return r;
}

// ---------- async global->LDS, 16B per lane, wave-uniform LDS base ----------
__device__ __forceinline__ void g2l16(const void* g, void* l) {
  __builtin_amdgcn_global_load_lds(
      (__attribute__((address_space(1))) void*)(uintptr_t)(g),
      (__attribute__((address_space(3))) void*)(l), 16, 0, 0);
}

// ---------------- fp32 -> fp16 elementwise ----------------
__global__ __launch_bounds__(256) void convk(const float* __restrict__ in,
                                             _Float16* __restrict__ out, int n) {
  int i = (blockIdx.x * 256 + threadIdx.x) * 4;
  if (i + 3 < n) {
    const float4 v = *(const float4*)(in + i);
    h4 o;
    o[0] = (_Float16)v.x; o[1] = (_Float16)v.y; o[2] = (_Float16)v.z; o[3] = (_Float16)v.w;
    *(h4*)(out + i) = o;
  }
}

// ---------------- fp32 [R][C] -> fp16 [C][R] transpose-convert ----------------
__global__ __launch_bounds__(256) void transconv_k(const float* __restrict__ in,
                                                   _Float16* __restrict__ out,
                                                   int R, int C) {
  __shared__ float tile[64][65];
  const int tC = C >> 6;
  const int bc = blockIdx.x % tC, br = blockIdx.x / tC;
  const int r0 = br << 6, c0 = bc << 6;
  const int t = threadIdx.x;
  const int lr = t >> 4, lc = (t & 15) << 2;
#pragma unroll
  for (int p = 0; p < 4; ++p) {
    const float4 v = *(const float4*)(in + (size_t)(r0 + p * 16 + lr) * C + c0 + lc);
    tile[p * 16 + lr][lc + 0] = v.x;
    tile[p * 16 + lr][lc + 1] = v.y;
    tile[p * 16 + lr][lc + 2] = v.z;
    tile[p * 16 + lr][lc + 3] = v.w;
  }
  __syncthreads();
#pragma unroll
  for (int p = 0; p < 4; ++p) {
    const int oc = p * 16 + lr;  // out-row = in-col
    h4 v;
#pragma unroll
    for (int e = 0; e < 4; ++e) v[e] = (_Float16)tile[lc + e][oc];
    *(h4*)(out + (size_t)(c0 + oc) * R + r0 + lc) = v;
  }
}

// ---- staging for the BK=32 kernel (gemm2): rows of 32 fp16 (64B), XOR (row&6)<<3 ----
__device__ __forceinline__ void stage_chunk(const _Float16* X, int R0, int K, int kof,
                                            _Float16* ldsbase, int chunk, int lane) {
  const int b = chunk * 1024 + lane * 16;           // linear LDS byte offset
  const int l = b ^ (((b >> 6) & 6) << 3);          // logical byte (involution)
  const _Float16* src = X + (size_t)(R0 + (l >> 6)) * K + kof + ((l & 63) >> 1);
  g2l16(src, (char*)ldsbase + chunk * 1024);
}

// ---------------- GEMM (gemm2): BM=256 BN=128 BK=32, 512 thr, 2-phase dbuf ----------------
// R12-measured best for MODE0. (124us-class structure: MfmaUtil 38.7%, VGPR 60.)
__global__ __launch_bounds__(512) void gemm_k(
    const _Float16* __restrict__ A, const _Float16* __restrict__ BT,
    const int K, const int NTILES, float* __restrict__ fo) {
  __shared__ __align__(16) _Float16 Ls[2][12288];  // [dbuf][A:8192 | B:4096] = 48KB
  const int tid = threadIdx.x;
  const int cpx = gridDim.x >> 3;
  const int xcd = blockIdx.x & 7, idx = blockIdx.x >> 3;
  const int MBC = cpx / NTILES;
  const int grp = idx >> 3, sub = idx & 7;
  const int bt = grp * 4 + (sub & 3);
  const int mb = xcd * MBC + (sub >> 2);
  const int m0 = mb * 256, n0 = bt * 128;
  const int wid = tid >> 6, lane = tid & 63;
  const int wr = wid >> 1, wc = wid & 1;  // 4 x 2 waves
  const int g = lane >> 4, c = lane & 15;

  f32x4 acc[4][4];
#pragma unroll
  for (int i = 0; i < 4; ++i)
#pragma unroll
    for (int j = 0; j < 4; ++j)
#pragma unroll
      for (int e = 0; e < 4; ++e) acc[i][j][e] = 0.f;

  const int sx = (c & 6) << 3;
  const int nk = K >> 5;

#pragma unroll
  for (int t0 = 0; t0 < 2; ++t0) {
    stage_chunk(A, m0, K, t0 * 32, Ls[t0], (0 * 8 + wid), lane);
    stage_chunk(A, m0, K, t0 * 32, Ls[t0], (1 * 8 + wid), lane);
    stage_chunk(BT, n0, K, t0 * 32, Ls[t0] + 8192, wid, lane);
  }

  for (int kt = 0; kt < nk; ++kt) {
    if (kt < nk - 1) {
      asm volatile("s_waitcnt vmcnt(3)" ::: "memory");
    } else {
      asm volatile("s_waitcnt vmcnt(0)" ::: "memory");
    }
    __builtin_amdgcn_s_barrier();
    const int db = kt & 1;
    const _Float16* Ab = Ls[db];
    const _Float16* Bb = Ls[db] + 8192;
    h8 af[4], bf[4];
#pragma unroll
    for (int t = 0; t < 4; ++t) {
      const int lg = (wr * 64 + t * 16 + c) * 64 + 16 * g;
      af[t] = *(const h8*)((const char*)Ab + (lg ^ sx));
    }
#pragma unroll
    for (int t = 0; t < 4; ++t) {
      const int lg = (wc * 64 + t * 16 + c) * 64 + 16 * g;
      bf[t] = *(const h8*)((const char*)Bb + (lg ^ sx));
    }
    __builtin_amdgcn_s_setprio(1);
#pragma unroll
    for (int i = 0; i < 4; ++i)
#pragma unroll
      for (int j = 0; j < 4; ++j)
        acc[i][j] = __builtin_amdgcn_mfma_f32_16x16x32_f16(af[i], bf[j], acc[i][j], 0, 0, 0);
    __builtin_amdgcn_s_setprio(0);
    __builtin_amdgcn_s_barrier();
    const int nx = kt + 2;
    if (nx < nk) {
      stage_chunk(A, m0, K, nx * 32, Ls[db], (0 * 8 + wid), lane);
      stage_chunk(A, m0, K, nx * 32, Ls[db], (1 * 8 + wid), lane);
      stage_chunk(BT, n0, K, nx * 32, Ls[db] + 8192, wid, lane);
    }
  }

  const int Ncols = NTILES * 128;
#pragma unroll
  for (int mt = 0; mt < 4; ++mt)
#pragma unroll
    for (int i = 0; i < 4; ++i) {
      const int m = m0 + wr * 64 + mt * 16 + 4 * g + i;
      float* orow = fo + (size_t)m * Ncols + n0 + wc * 64 + c;
#pragma unroll
      for (int nt = 0; nt < 4; ++nt) orow[nt * 16] = acc[mt][nt][i];
    }
}

// ---------------- GEMM1 (QKV): BK=64 counted-vmcnt pipeline (T4-faithful) ----------------
// BM=256 BN=128 BK=64, 512 thr (8 waves 4x2, 64x64/wave, acc[4][4]; epilogue identical).
// LDS 96KB = 2 dbuf x [A 256x64 | B 128x64]. 2 barriers per K-tile, NO vmcnt(0) drain
// in steady state:
//   top:    vmcnt(6)  -- oldest 6 loads (tile kt) landed; tile kt+1's 6 stay in flight
//           s_barrier -- tile kt published to all waves
//   body:   16 ds_read_b128; lgkmcnt(8)+sched_barrier -> 16 MFMA (kk=0);
//           lgkmcnt(0)+sched_barrier -> 16 MFMA (kk=1)
//   bottom: s_barrier -- every wave's reads of buf[kt&1] are done (lgkmcnt(0) preceded
//           its MFMA which preceded this barrier) -> stage tile kt+2 into buf[kt&1]
// Ledger: in-flight at top of kt = {kt:6 oldest, kt+1:6} (prologue stages 0,1; bottom
// of kt stages kt+2) -> vmcnt(6) == tile kt resident. Last tile: vmcnt(0).
// Swizzle (128B rows): phys = log ^ (((log>>7)&7)<<4); staging pre-swizzles the global
// source, LDS stays linear (both-sides rule); reads conflict-free (verified R16, abs ok).
__global__ __launch_bounds__(512) void gemm8_k(
    const _Float16* __restrict__ A, const _Float16* __restrict__ BT,
    const int K, const int NTILES,
    _Float16* __restrict__ outq, _Float16* __restrict__ outk,
    _Float16* __restrict__ outv, const float* __restrict__ freqs) {
  __shared__ __align__(16) _Float16 Ls[2][24576];  // 96KB
  const int tid = threadIdx.x;
  const int cpx = gridDim.x >> 3;
  const int xcd = blockIdx.x & 7, idx = blockIdx.x >> 3;
  const int MBC = cpx / NTILES;
  const int grp = idx >> 3, sub = idx & 7;
  const int bt = grp * 4 + (sub & 3);
  const int mb = xcd * MBC + (sub >> 2);
  const int m0 = mb * 256, n0 = bt * 128;
  const int wid = tid >> 6, lane = tid & 63;
  const int wr = wid >> 1, wc = wid & 1;  // 4 x 2 waves
  const int g = lane >> 4, c = lane & 15;

  f32x4 acc[4][4];
#pragma unroll
  for (int i = 0; i < 4; ++i)
#pragma unroll
    for (int j = 0; j < 4; ++j)
#pragma unroll
      for (int e = 0; e < 4; ++e) acc[i][j][e] = 0.f;

  // staging sources (per-lane, pre-swizzled) + wave-uniform LDS dests
  const _Float16* srcA[4];
  int dstA[4];
#pragma unroll
  for (int a = 0; a < 4; ++a) {
    const int h = a >> 1, q = a & 1;
    const int d = h * 16384 + q * 8192 + wid * 1024;  // dest byte in A region
    const int b = d + lane * 16;
    const int l = b ^ (((b >> 7) & 7) << 4);
    srcA[a] = A + (size_t)(m0 + (l >> 7)) * K + ((l & 127) >> 1);
    dstA[a] = d;
  }
  const _Float16* srcB[2];
  int dstB[2];
#pragma unroll
  for (int q = 0; q < 2; ++q) {
    const int d = q * 8192 + wid * 1024;              // region-local
    const int b = d + lane * 16;
    const int l = b ^ (((b >> 7) & 7) << 4);
    srcB[q] = BT + (size_t)(n0 + (l >> 7)) * K + ((l & 127) >> 1);
    dstB[q] = 32768 + d;                               // B region starts at byte 32768
  }

  // fragment read byte-offsets (loop-invariant)
  int aoff[2][4], boff[2][4];
#pragma unroll
  for (int kk = 0; kk < 2; ++kk)
#pragma unroll
    for (int t = 0; t < 4; ++t) {
      const int ra = (wr * 64 + t * 16 + c);
      const int rb = (wc * 64 + t * 16 + c);
      aoff[kk][t] = (ra * 128 + kk * 64 + 16 * g) ^ ((c & 7) << 4);
      boff[kk][t] = 32768 + ((rb * 128 + kk * 64 + 16 * g) ^ ((c & 7) << 4));
    }

  const int nk = K >> 6;  // K-tiles of 64

  // prologue: stage tile 0 -> buf0 and tile 1 -> buf1 (12 loads in flight)
#pragma unroll
  for (int a = 0; a < 4; ++a) g2l16(srcA[a], (char*)Ls[0] + dstA[a]);
#pragma unroll
  for (int q = 0; q < 2; ++q) g2l16(srcB[q], (char*)Ls[0] + dstB[q]);
#pragma unroll
  for (int a = 0; a < 4; ++a) g2l16(srcA[a] + 64, (char*)Ls[1] + dstA[a]);
#pragma unroll
  for (int q = 0; q < 2; ++q) g2l16(srcB[q] + 64, (char*)Ls[1] + dstB[q]);

  for (int kt = 0; kt < nk; ++kt) {
    if (kt < nk - 1) {
      asm volatile("s_waitcnt vmcnt(6)" ::: "memory");  // tile kt landed; kt+1 in flight
    } else {
      asm volatile("s_waitcnt vmcnt(0)" ::: "memory");  // last tile
    }
    __builtin_amdgcn_s_barrier();  // tile kt published
    const char* Lb = (const char*)Ls[kt & 1];

    h8 af0[4], bf0[4], af1[4], bf1[4];
#pragma unroll
    for (int t = 0; t < 4; ++t) af0[t] = *(const h8*)(Lb + aoff[0][t]);
#pragma unroll
    for (int t = 0; t < 4; ++t) bf0[t] = *(const h8*)(Lb + boff[0][t]);
#pragma unroll
    for (int t = 0; t < 4; ++t) af1[t] = *(const h8*)(Lb + aoff[1][t]);
#pragma unroll
    for (int t = 0; t < 4; ++t) bf1[t] = *(const h8*)(Lb + boff[1][t]);

    asm volatile("s_waitcnt lgkmcnt(8)" ::: "memory");  // first 8 reads (af0,bf0) done
    __builtin_amdgcn_sched_barrier(0);
    __builtin_amdgcn_s_setprio(1);
#pragma unroll
    for (int i = 0; i < 4; ++i)
#pragma unroll
      for (int j = 0; j < 4; ++j)
        acc[i][j] = __builtin_amdgcn_mfma_f32_16x16x32_f16(af0[i], bf0[j], acc[i][j], 0, 0, 0);
    __builtin_amdgcn_s_setprio(0);

    asm volatile("s_waitcnt lgkmcnt(0)" ::: "memory");  // all 16 reads done
    __builtin_amdgcn_sched_barrier(0);
    __builtin_amdgcn_s_setprio(1);
#pragma unroll
    for (int i = 0; i < 4; ++i)
#pragma unroll
      for (int j = 0; j < 4; ++j)
        acc[i][j] = __builtin_amdgcn_mfma_f32_16x16x32_f16(af1[i], bf1[j], acc[i][j], 0, 0, 0);
    __builtin_amdgcn_s_setprio(0);

    __builtin_amdgcn_s_barrier();  // all waves finished reading buf[kt&1]
    if (kt + 2 < nk) {             // overwrite buf[kt&1] with tile kt+2
      const int kof = (kt + 2) << 6;
      char* Ln = (char*)Ls[kt & 1];
#pragma unroll
      for (int a = 0; a < 4; ++a) g2l16(srcA[a] + kof, Ln + dstA[a]);
#pragma unroll
      for (int q = 0; q < 2; ++q) g2l16(srcB[q] + kof, Ln + dstB[q]);
    }
  }

  // ---- MODE1 epilogue (identical to proven kernel) ----
  const int hh = ((bt & 15) << 1) | wc;  // head 0..31 within its third
  const int third = bt >> 4;             // 0=q 1=k 2=v
  if (third < 2) {
    _Float16* dst0 = (third == 0) ? outq : outk;
#pragma unroll
    for (int mt = 0; mt < 4; ++mt) {
      float ss[4];
#pragma unroll
      for (int i = 0; i < 4; ++i) {
        float s = 0.f;
#pragma unroll
        for (int nt = 0; nt < 4; ++nt) { const float v = acc[mt][nt][i]; s += v * v; }
        ss[i] = s;
      }
#pragma unroll
      for (int msk = 1; msk < 16; msk <<= 1)
#pragma unroll
        for (int i = 0; i < 4; ++i) ss[i] += __shfl_xor(ss[i], msk);
#pragma unroll
      for (int i = 0; i < 4; ++i) {
        const int m = m0 + wr * 64 + mt * 16 + 4 * g + i;
        const int b = m >> 11, pos = m & 2047;
        float inv = 1.0f / fmaxf(sqrtf(ss[i]), 1e-12f);
        if (third == 0) inv *= 0.1803368801f;  // 0.125 * log2(e) folded into q
        const float v0 = acc[mt][0][i] * inv, v1 = acc[mt][1][i] * inv;
        const float v2 = acc[mt][2][i] * inv, v3 = acc[mt][3][i] * inv;
        float sn, cs;
        __sincosf(freqs[pos * 32 + c], &sn, &cs);
        _Float16* d = dst0 + ((size_t)((b << 5) | hh) * 64 + (pos >> 5)) * 2048 +
                      ((c >> 3) * 32 + (pos & 31)) * 8 + (c & 7);
        d[0]    = (_Float16)(v0 * cs - v1 * sn);
        d[512]  = (_Float16)(v1 * cs + v0 * sn);
        d[1024] = (_Float16)v2;
        d[1536] = (_Float16)v3;
      }
    }
  } else {
#pragma unroll
    for (int mt = 0; mt < 4; ++mt)
#pragma unroll
      for (int i = 0; i < 4; ++i) {
        const int m = m0 + wr * 64 + mt * 16 + 4 * g + i;
        const int b = m >> 11, pos = m & 2047;
        const int kvb = pos >> 5, sub2 = (pos >> 4) & 1, rem = pos & 15;
        const int vhi = (rem >> 2) & 1;
        const int vj = (rem & 3) + ((rem >> 3) << 2);
        const size_t hbase = ((size_t)((b << 5) | hh) * 64 + kvb) * 2048;
#pragma unroll
        for (int nt = 0; nt < 4; ++nt) {
          const int dta = nt >> 1;
          const int lfrag = vhi * 32 + (nt & 1) * 16 + c;
          outv[hbase + ((dta * 2 + sub2) * 64 + lfrag) * 8 + vj] = (_Float16)acc[mt][nt][i];
        }
      }
  }
}

// ---------------- flash attention (R15-frozen): swapped QK^T, reg-dbuf K/V ----------------
__global__ __launch_bounds__(256) void attn_k(const _Float16* __restrict__ qf_,
                                              const _Float16* __restrict__ kf_,
                                              const _Float16* __restrict__ vf_,
                                              _Float16* __restrict__ attno) {
  const int tid = threadIdx.x;
  const int wid = tid >> 6;
  const int lane = tid & 63;
  const int l31 = tid & 31;
  const int hi = (tid >> 5) & 1;
  const int dd = blockIdx.x;
  const int xcd = dd & 7, j = dd >> 3;
  const int bh = xcd * 8 + (j >> 4);
  const int qg = j & 15;
  const int qb = (qg << 2) | wid;
  const int q = qb * 32 + l31;

  const _Float16* qp = qf_ + ((size_t)bh * 64 + qb) * 2048 + lane * 8;
  h8 qfr[4];
#pragma unroll
  for (int dc = 0; dc < 4; ++dc) qfr[dc] = *(const h8*)(qp + dc * 512);

  const _Float16* kp = kf_ + (size_t)bh * 64 * 2048 + lane * 8;
  const _Float16* vp = vf_ + (size_t)bh * 64 * 2048 + lane * 8;

  f32x16 acc0, acc1;
#pragma unroll
  for (int e = 0; e < 16; ++e) { acc0[e] = 0.f; acc1[e] = 0.f; }
  float l0 = 0.f, l1 = 0.f, l2 = 0.f, l3 = 0.f;

  auto compute = [&](h8 k0, h8 k1, h8 k2, h8 k3, h8 w00, h8 w01, h8 w10, h8 w11) {
    f32x16 S;
#pragma unroll
    for (int e = 0; e < 16; ++e) S[e] = 0.f;
    __builtin_amdgcn_s_setprio(1);
    S = __builtin_amdgcn_mfma_f32_32x32x16_f16(k0, qfr[0], S, 0, 0, 0);
    S = __builtin_amdgcn_mfma_f32_32x32x16_f16(k1, qfr[1], S, 0, 0, 0);
    S = __builtin_amdgcn_mfma_f32_32x32x16_f16(k2, qfr[2], S, 0, 0, 0);
    S = __builtin_amdgcn_mfma_f32_32x32x16_f16(k3, qfr[3], S, 0, 0, 0);
    __builtin_amdgcn_s_setprio(0);
    float p[16];
#pragma unroll
    for (int e = 0; e < 16; ++e) p[e] = exp2_raw(S[e]);
    l0 += p[0]; l1 += p[1]; l2 += p[2]; l3 += p[3];
    l0 += p[4]; l1 += p[5]; l2 += p[6]; l3 += p[7];
    l0 += p[8]; l1 += p[9]; l2 += p[10]; l3 += p[11];
    l0 += p[12]; l1 += p[13]; l2 += p[14]; l3 += p[15];
    h2 c0 = cvt_pk(p[0], p[1]);
    h2 c1 = cvt_pk(p[2], p[3]);
    h2 c2 = cvt_pk(p[4], p[5]);
    h2 c3 = cvt_pk(p[6], p[7]);
    h2 c4 = cvt_pk(p[8], p[9]);
    h2 c5 = cvt_pk(p[10], p[11]);
    h2 c6 = cvt_pk(p[12], p[13]);
    h2 c7 = cvt_pk(p[14], p[15]);
    h4 x0 = __builtin_shufflevector(c0, c1, 0, 1, 2, 3);
    h4 x1 = __builtin_shufflevector(c2, c3, 0, 1, 2, 3);
    h4 x2 = __builtin_shufflevector(c4, c5, 0, 1, 2, 3);
    h4 x3 = __builtin_shufflevector(c6, c7, 0, 1, 2, 3);
    h8 pb0 = __builtin_shufflevector(x0, x1, 0, 1, 2, 3, 4, 5, 6, 7);
    h8 pb1 = __builtin_shufflevector(x2, x3, 0, 1, 2, 3, 4, 5, 6, 7);
    __builtin_amdgcn_s_setprio(1);
    acc0 = __builtin_amdgcn_mfma_f32_32x32x16_f16(w00, pb0, acc0, 0, 0, 0);
    acc0 = __builtin_amdgcn_mfma_f32_32x32x16_f16(w01, pb1, acc0, 0, 0, 0);
    acc1 = __builtin_amdgcn_mfma_f32_32x32x16_f16(w10, pb0, acc1, 0, 0, 0);
    acc1 = __builtin_amdgcn_mfma_f32_32x32x16_f16(w11, pb1, acc1, 0, 0, 0);
    __builtin_amdgcn_s_setprio(0);
  };

  h8 kA0 = *(const h8*)(kp);
  h8 kA1 = *(const h8*)(kp + 512);
  h8 kA2 = *(const h8*)(kp + 1024);
  h8 kA3 = *(const h8*)(kp + 1536);
  h8 vA0 = *(const h8*)(vp);
  h8 vA1 = *(const h8*)(vp + 512);
  h8 vA2 = *(const h8*)(vp + 1024);
  h8 vA3 = *(const h8*)(vp + 1536);

  for (int it = 0; it < 64; it += 2) {
    const _Float16* kb1 = kp + (size_t)(it + 1) * 2048;
    const _Float16* vb1 = vp + (size_t)(it + 1) * 2048;
    h8 kB0 = *(const h8*)(kb1);
    h8 kB1 = *(const h8*)(kb1 + 512);
    h8 kB2 = *(const h8*)(kb1 + 1024);
    h8 kB3 = *(const h8*)(kb1 + 1536);
    h8 vB0 = *(const h8*)(vb1);
    h8 vB1 = *(const h8*)(vb1 + 512);
    h8 vB2 = *(const h8*)(vb1 + 1024);
    h8 vB3 = *(const h8*)(vb1 + 1536);

    compute(kA0, kA1, kA2, kA3, vA0, vA1, vA2, vA3);

    if (it + 2 < 64) {
      const _Float16* kb2 = kp + (size_t)(it + 2) * 2048;
      const _Float16* vb2 = vp + (size_t)(it + 2) * 2048;
      kA0 = *(const h8*)(kb2);
      kA1 = *(const h8*)(kb2 + 512);
      kA2 = *(const h8*)(kb2 + 1024);
      kA3 = *(const h8*)(kb2 + 1536);
      vA0 = *(const h8*)(vb2);
      vA1 = *(const h8*)(vb2 + 512);
      vA2 = *(const h8*)(vb2 + 1024);
      vA3 = *(const h8*)(vb2 + 1536);
    }

    compute(kB0, kB1, kB2, kB3, vB0, vB1, vB2, vB3);
  }

  float lsum = (l0 + l1) + (l2 + l3);
  lsum += __shfl_xor(lsum, 32);
  const float inv = 1.0f / lsum;

  const int b = bh >> 5, h = bh & 31;
  _Float16* orow = attno + ((size_t)b * 2048 + q) * 2048 + h * 64;
#pragma unroll
  for (int dta = 0; dta < 2; ++dta) {
#pragma unroll
    for (int blk = 0; blk < 4; ++blk) {
      h4 st;
#pragma unroll
      for (int e = 0; e < 4; ++e) {
        const float v = (dta == 0) ? acc0[blk * 4 + e] : acc1[blk * 4 + e];
        st[e] = (_Float16)(v * inv);
      }
      *(h4*)(orow + dta * 32 + blk * 8 + 4 * hi) = st;
    }
  }
}

extern "C" void kernel_launch(void* const* d_in, const int* in_sizes, int n_in,
                              void* d_out, int out_size, void* d_ws, size_t ws_size,
                              hipStream_t stream) {
  const float* x = (const float*)d_in[0];
  const float* wqkv = (const float*)d_in[1];
  const float* wout = (const float*)d_in[2];
  const float* freqs = (const float*)d_in[3];
  char* ws = (char*)d_ws;
  _Float16* xb    = (_Float16*)ws;                          // [0,16M)  gemm1 A input
  _Float16* attno = xb;                                     // [0,16M)  attn out (x dead)
  _Float16* wqkvT = (_Float16*)(ws + (size_t)(16 << 20));   // [16,40M) gemm1 B input
  _Float16* woutT = (_Float16*)(ws + (size_t)(40 << 20));   // [40,48M)
  _Float16* qn    = (_Float16*)(ws + (size_t)(48 << 20));   // [48,64M) q-frags
  _Float16* kn    = (_Float16*)(ws + (size_t)(64 << 20));   // [64,80M) k-frags
  _Float16* vT    = (_Float16*)(ws + (size_t)(80 << 20));   // [80,96M) v-frags
  float* out = (float*)d_out;

  convk<<<8192, 256, 0, stream>>>(x, xb, 2 * 2048 * 2048);
  transconv_k<<<(6144 / 64) * (2048 / 64), 256, 0, stream>>>(wqkv, wqkvT, 2048, 6144);
  transconv_k<<<(2048 / 64) * (2048 / 64), 256, 0, stream>>>(wout, woutT, 2048, 2048);
  gemm8_k<<<16 * 48, 512, 0, stream>>>(xb, wqkvT, 2048, 48, qn, kn, vT, freqs);
  attn_k<<<1024, 256, 0, stream>>>(qn, kn, vT, attno);
  gemm_k<<<16 * 16, 512, 0, stream>>>(attno, woutT, 2048, 16, out);
}